// Round 3
// baseline (89.586 us; speedup 1.0000x reference)
//
#include <hip/hip_runtime.h>
#include <hip/hip_bf16.h>
#include <math.h>

#define BATCH 4096
#define NROWS 8192
#define DIM   128
#define NTILE 64                         // 8192 / 128 row/col blocks
#define NBLK  (NTILE * (NTILE + 1) / 2)  // 2080 lower-triangle tiles

typedef __bf16 bf16x8 __attribute__((ext_vector_type(8)));
typedef __bf16 bf16x2 __attribute__((ext_vector_type(2)));
typedef float  f32x4  __attribute__((ext_vector_type(4)));

typedef const __attribute__((address_space(1))) unsigned int* gptr_t;
typedef __attribute__((address_space(3))) unsigned int* lptr_t;

// ---------------------------------------------------------------------------
// Kernel 1: row-normalize z = concat(zx, zy), write bf16 zn [8192 x 128]
// One wave per row; lane holds 2 floats.
// ---------------------------------------------------------------------------
__global__ __launch_bounds__(256) void normalize_kernel(
    const float* __restrict__ zx, const float* __restrict__ zy,
    ushort* __restrict__ zn)
{
  const int tid  = threadIdx.x;
  const int lane = tid & 63;
  const int w    = tid >> 6;
  const int row  = blockIdx.x * 4 + w;
  const float* src = (row < BATCH) ? (zx + (size_t)row * DIM)
                                   : (zy + (size_t)(row - BATCH) * DIM);
  float2 v = ((const float2*)src)[lane];
  float ss = v.x * v.x + v.y * v.y;
#pragma unroll
  for (int off = 1; off < 64; off <<= 1)
    ss += __shfl_xor(ss, off, 64);
  float inv = 1.0f / fmaxf(sqrtf(ss), 1e-8f);
  bf16x2 st;
  st.x = (__bf16)(v.x * inv);
  st.y = (__bf16)(v.y * inv);
  reinterpret_cast<bf16x2*>(zn + (size_t)row * DIM)[lane] = st;
}

// ---------------------------------------------------------------------------
// Kernel 2 (v3): SYMMETRY-HALVED fused sim/exp-sum.
// sim = zn zn^T is symmetric -> compute only the 2080 lower-triangle 128x128
// tiles (rb, cb<=rb). Each tile's exp values feed BOTH:
//   row-side: rows of rb-block  -> Spart[slot=cb][rb*128 + r]
//   col-side: rows of cb-block  -> Spart[slot=rb][cb*128 + c]  (skip if diag)
// Each (slot, row) cell has exactly ONE writer (the (max,min) tile of the
// pair), so no atomics / memsets. finalize sums the 64 slots per row.
// Positive pairs: tile (rb, rb-32) holds sim[i, i-4096]; write P[i] and
// P[i-4096] (symmetric). Diagonal tiles zero their own diagonal, row-side only.
//
// Per block: A-frags (rb rows) in registers; B tile (cb rows) staged to LDS
// via global_load_lds(16B) with XOR chunk swizzle. One tile per block;
// 2 blocks/CU overlap each other (cross-block TLP hides staging).
// ---------------------------------------------------------------------------
__global__ __launch_bounds__(256, 2) void simloss_kernel(
    const ushort* __restrict__ zn, float* __restrict__ Spart,
    float* __restrict__ P)
{
  __shared__ ushort Bs[128 * 128];   // 32 KiB swizzled B tile; f32 scratch later
  const int tid  = threadIdx.x;
  const int lane = tid & 63;
  const int w    = tid >> 6;
  const int wr   = w >> 1, wc = w & 1;
  const int q    = lane >> 4;     // quad 0..3
  const int l15  = lane & 15;

  // Decode lower-triangle tile (rb, cb) from linear block id (integer-only).
  const int b = blockIdx.x;
  int rb = 0;
  {
    int lo = 0, hi = NTILE - 1;
    while (lo < hi) {                       // find rb: rb*(rb+1)/2 <= b < ...
      int mid = (lo + hi + 1) >> 1;
      if (mid * (mid + 1) / 2 <= b) lo = mid; else hi = mid - 1;
    }
    rb = lo;
  }
  const int cb = b - rb * (rb + 1) / 2;        // 0..rb
  const bool diag = (rb == cb);

  // Stage B tile (cb block rows). Chunk (row, c) -> LDS chunk row*16 +
  // (c ^ (row&15)); global_load_lds dest is uniform base + lane*16, so the
  // swizzle is applied on the per-lane GLOBAL source address.
  {
    const int C0 = cb * 128;
#pragma unroll
    for (int j = 0; j < 8; ++j) {
      const int Lbase = w * 512 + j * 64;          // uniform per wave
      const int row   = w * 32 + j * 4 + q;        // (Lbase+lane)>>4
      const int c     = l15 ^ (row & 15);
      const ushort* g = zn + (size_t)(C0 + row) * DIM + c * 8;
      __builtin_amdgcn_global_load_lds((gptr_t)g, (lptr_t)(Bs + Lbase * 8), 16, 0, 0);
    }
  }

  // A fragments: rows rb*128 + wr*64 + mi*16 + l15, k = q*8 + j within ks*32
  bf16x8 af[4][4];
  {
    const int arow = rb * 128 + wr * 64 + l15;
#pragma unroll
    for (int mi = 0; mi < 4; ++mi)
#pragma unroll
      for (int ks = 0; ks < 4; ++ks) {
        const ushort* ap = zn + (size_t)(arow + mi * 16) * DIM + ks * 32 + q * 8;
        af[mi][ks] = *reinterpret_cast<const bf16x8*>(ap);
      }
  }

  __syncthreads();  // compiler drains vmcnt(0) before s_barrier: B tile ready

  f32x4 acc[4][4];
#pragma unroll
  for (int mi = 0; mi < 4; ++mi)
#pragma unroll
    for (int ni = 0; ni < 4; ++ni)
      acc[mi][ni] = (f32x4){0.f, 0.f, 0.f, 0.f};

#pragma unroll
  for (int ks = 0; ks < 4; ++ks) {
    bf16x8 bf[4];
#pragma unroll
    for (int ni = 0; ni < 4; ++ni) {
      const int nl  = wc * 64 + ni * 16 + l15;   // B row in tile (sim col)
      const int ck  = ks * 4 + q;                // k-chunk 0..15
      const int L   = nl * 16 + (ck ^ (nl & 15));
      bf[ni] = *reinterpret_cast<const bf16x8*>(Bs + L * 8);
    }
#pragma unroll
    for (int mi = 0; mi < 4; ++mi)
#pragma unroll
      for (int ni = 0; ni < 4; ++ni)
        acc[mi][ni] = __builtin_amdgcn_mfma_f32_16x16x32_bf16(
            af[mi][ks], bf[ni], acc[mi][ni], 0, 0, 0);
  }

  // Epilogue: v = exp(sim - 2) = exp2(K1*dot - K1); accumulate row & col sums.
  const float K1 = 2.8853900817779268f;  // (1/TEMP) * log2(e)
  float Srow[4][4];
  float Scol[4];
#pragma unroll
  for (int mi = 0; mi < 4; ++mi)
#pragma unroll
    for (int r = 0; r < 4; ++r) Srow[mi][r] = 0.f;
#pragma unroll
  for (int ni = 0; ni < 4; ++ni) Scol[ni] = 0.f;

#pragma unroll
  for (int mi = 0; mi < 4; ++mi)
#pragma unroll
    for (int ni = 0; ni < 4; ++ni)
#pragma unroll
      for (int r = 0; r < 4; ++r) {
        float d = acc[mi][ni][r];
        float v = __builtin_amdgcn_exp2f(fmaf(d, K1, -K1));
        if (diag) {
          const int rl = wr * 64 + mi * 16 + q * 4 + r;
          const int cl = wc * 64 + ni * 16 + l15;
          if (rl == cl) v = 0.f;
        }
        Srow[mi][r] += v;
        Scol[ni]    += v;
      }

  // Positive pairs: tile (rb, rb-32) has sim[i, i-4096] at local rl==cl.
  if (rb >= 32 && cb == rb - 32) {
#pragma unroll
    for (int mi = 0; mi < 4; ++mi) {
      const int rl0 = wr * 64 + mi * 16 + q * 4;
#pragma unroll
      for (int ni = 0; ni < 4; ++ni) {
        const int cl = wc * 64 + ni * 16 + l15;
#pragma unroll
        for (int r = 0; r < 4; ++r) {
          if (cl == rl0 + r) {
            const int gr = rb * 128 + rl0 + r;
            const float pv = 2.0f * acc[mi][ni][r];
            P[gr] = pv;
            P[gr - 4096] = pv;   // symmetric partner
          }
        }
      }
    }
  }

  // Cross-lane reductions.
  // Row sums: reduce over l15 (16 lanes share a row-group).
#pragma unroll
  for (int mi = 0; mi < 4; ++mi)
#pragma unroll
    for (int r = 0; r < 4; ++r) {
      float v = Srow[mi][r];
      v += __shfl_xor(v, 1, 64);
      v += __shfl_xor(v, 2, 64);
      v += __shfl_xor(v, 4, 64);
      v += __shfl_xor(v, 8, 64);
      Srow[mi][r] = v;   // all 16 lanes of the quad hold the sum
    }
  // Col sums: reduce over the 4 quads (lanes l15, l15+16, l15+32, l15+48).
#pragma unroll
  for (int ni = 0; ni < 4; ++ni) {
    float v = Scol[ni];
    v += __shfl_xor(v, 16, 64);
    v += __shfl_xor(v, 32, 64);
    Scol[ni] = v;        // all lanes hold the col sum for (ni, l15)
  }

  // Combine wave pairs through LDS (Bs is dead after the barrier).
  __syncthreads();                 // all ds_reads of Bs complete in all waves
  float* sc = (float*)Bs;          // [0,256): rows as [wc][128]; [256,512): cols as [wr][128]
  if (l15 == 0) {
#pragma unroll
    for (int mi = 0; mi < 4; ++mi)
#pragma unroll
      for (int r = 0; r < 4; ++r)
        sc[wc * 128 + wr * 64 + mi * 16 + q * 4 + r] = Srow[mi][r];
  }
  if (lane < 16) {                 // q == 0 lanes
#pragma unroll
    for (int ni = 0; ni < 4; ++ni)
      sc[256 + wr * 128 + wc * 64 + ni * 16 + l15] = Scol[ni];
  }
  __syncthreads();

  if (tid < 128) {
    // row-side: rows of rb-block, slot cb (unique writer: this block)
    Spart[(size_t)cb * NROWS + rb * 128 + tid] = sc[tid] + sc[128 + tid];
  } else if (!diag) {
    // col-side: rows of cb-block, slot rb (unique writer: this block)
    const int c = tid - 128;
    Spart[(size_t)rb * NROWS + cb * 128 + c] = sc[256 + c] + sc[384 + c];
  }
}

// ---------------------------------------------------------------------------
// Kernel 3: loss = mean_i( 2 + log(sum_s Spart[s][i]) - P_i )
// ---------------------------------------------------------------------------
__global__ __launch_bounds__(256) void finalize_kernel(
    const float* __restrict__ Spart, const float* __restrict__ P,
    float* __restrict__ out)
{
  const int i = blockIdx.x * 256 + threadIdx.x;
  float s = 0.f;
#pragma unroll 16
  for (int k = 0; k < NTILE; ++k) s += Spart[(size_t)k * NROWS + i];
  float c = 2.0f + logf(s) - P[i];
#pragma unroll
  for (int off = 1; off < 64; off <<= 1)
    c += __shfl_xor(c, off, 64);
  __shared__ float wsum[4];
  const int lane = threadIdx.x & 63, w = threadIdx.x >> 6;
  if (lane == 0) wsum[w] = c;
  __syncthreads();
  if (threadIdx.x == 0)
    atomicAdd(out, (wsum[0] + wsum[1] + wsum[2] + wsum[3]) * (1.0f / NROWS));
}

// ---------------------------------------------------------------------------
extern "C" void kernel_launch(void* const* d_in, const int* in_sizes, int n_in,
                              void* d_out, int out_size, void* d_ws, size_t ws_size,
                              hipStream_t stream)
{
  const float* zx = (const float*)d_in[0];
  const float* zy = (const float*)d_in[1];
  ushort* zn = (ushort*)d_ws;                                      // 2 MiB bf16
  float*  P  = (float*)((char*)d_ws + (size_t)NROWS * DIM * 2);    // 32 KiB
  float*  Sp = P + NROWS;                                          // 2 MiB
  float*  out = (float*)d_out;

  hipMemsetAsync(out, 0, sizeof(float), stream);
  normalize_kernel<<<NROWS / 4, 256, 0, stream>>>(zx, zy, zn);
  simloss_kernel<<<NBLK, 256, 0, stream>>>(zn, Sp, P);
  finalize_kernel<<<NROWS / 256, 256, 0, stream>>>(Sp, P, out);
}

// Round 4
// 86.399 us; speedup vs baseline: 1.0369x; 1.0369x over previous
//
#include <hip/hip_runtime.h>
#include <hip/hip_bf16.h>

#define BATCH 4096
#define NROWS 8192
#define DIM   128
#define NTILE 64

typedef __bf16 bf16x8 __attribute__((ext_vector_type(8)));
typedef __bf16 bf16x2 __attribute__((ext_vector_type(2)));
typedef float  f32x4  __attribute__((ext_vector_type(4)));

typedef const __attribute__((address_space(1))) unsigned int* gptr_t;
typedef __attribute__((address_space(3))) unsigned int* lptr_t;

// ---------------------------------------------------------------------------
// Kernel 1: row-normalize z = concat(zx, zy) -> bf16 zn [8192 x 128].
// One wave per row. Also zero-initializes S (8192 floats) so simloss can
// accumulate with atomics into poisoned workspace (blocks 0..31).
// ---------------------------------------------------------------------------
__global__ __launch_bounds__(256) void normalize_kernel(
    const float* __restrict__ zx, const float* __restrict__ zy,
    ushort* __restrict__ zn, float* __restrict__ S)
{
  const int tid  = threadIdx.x;
  const int lane = tid & 63;
  const int w    = tid >> 6;
  const int row  = blockIdx.x * 4 + w;
  if (blockIdx.x < 32) S[blockIdx.x * 256 + tid] = 0.f;
  const float* src = (row < BATCH) ? (zx + (size_t)row * DIM)
                                   : (zy + (size_t)(row - BATCH) * DIM);
  float2 v = ((const float2*)src)[lane];
  float ss = v.x * v.x + v.y * v.y;
#pragma unroll
  for (int off = 1; off < 64; off <<= 1)
    ss += __shfl_xor(ss, off, 64);
  float inv = 1.0f / fmaxf(sqrtf(ss), 1e-8f);
  bf16x2 st;
  st.x = (__bf16)(v.x * inv);
  st.y = (__bf16)(v.y * inv);
  reinterpret_cast<bf16x2*>(zn + (size_t)row * DIM)[lane] = st;
}

// ---------------------------------------------------------------------------
// Kernel 2 (v4): symmetry-halved + pipelined strips.
// Lower triangle (2080 tiles of 128x128) decomposed into 32 row-PAIRS
// {p, 63-p} of 65 tiles each (row rb has rb+1 tiles, cb=0..rb).
// Grid = 32 pairs x 16 chunks = 512 blocks (exactly 2/CU); chunk 0 takes
// 5 tiles, chunks 1..15 take 4 (contiguous in the pair's tile sequence, so
// each block sees at most ONE row switch -> at most one A-frag reload).
//
// Per tile, exp values feed BOTH row-block and col-block sums of the
// symmetric matrix (col-side skipped on diagonal tiles). Sums go to a single
// S[8192] via shfl-reduce + atomicAdd (S zeroed by normalize_kernel).
// Positive-pair tiles (rb-cb==32) write P[i] and mirror P[i-4096].
//
// B tiles double-buffered in LDS (2x32 KiB) with the round-1 schedule:
// stage(t+1) -> compute(t) -> barrier; stage latency hides under MFMA.
// A-fragments register-resident across the whole row run.
// ---------------------------------------------------------------------------
__global__ __launch_bounds__(256, 2) void simloss_kernel(
    const ushort* __restrict__ zn, float* __restrict__ S,
    float* __restrict__ P)
{
  __shared__ ushort Bs[2][128 * 128];   // 2 x 32 KiB swizzled B tiles
  const int tid  = threadIdx.x;
  const int lane = tid & 63;
  const int w    = tid >> 6;
  const int wr   = w >> 1, wc = w & 1;
  const int q    = lane >> 4;     // quad 0..3
  const int l15  = lane & 15;

  const int p  = blockIdx.x >> 4;            // pair 0..31: rows {p, 63-p}
  const int ch = blockIdx.x & 15;            // chunk 0..15
  const int o0 = (ch == 0) ? 0 : 1 + ch * 4; // seq start: 0,5,9,...,61
  const int T  = (ch == 0) ? 5 : 4;          // tiles in this chunk
  const int L0 = p + 1;                      // tiles in short row (rb = p)

  // seq position o -> tile (rb, cb)
  auto tile_rc = [&](int o, int& rb, int& cb) {
    if (o < L0) { rb = p;      cb = o; }
    else        { rb = 63 - p; cb = o - L0; }
  };

  // Stage B tile for col-block cb into Bs[buf]. Chunk (row, c) -> LDS chunk
  // row*16 + (c ^ (row&15)); global_load_lds dest is uniform base + lane*16,
  // so the swizzle is applied on the per-lane GLOBAL source address.
  auto stage = [&](int cb, int buf) {
    const int C0 = cb * 128;
#pragma unroll
    for (int j = 0; j < 8; ++j) {
      const int Lbase = w * 512 + j * 64;          // uniform per wave
      const int row   = w * 32 + j * 4 + q;        // (Lbase+lane)>>4
      const int c     = l15 ^ (row & 15);
      const ushort* g = zn + (size_t)(C0 + row) * DIM + c * 8;
      __builtin_amdgcn_global_load_lds((gptr_t)g, (lptr_t)(&Bs[buf][Lbase * 8]),
                                       16, 0, 0);
    }
  };

  // A fragments: rows rb*128 + wr*64 + mi*16 + l15, k chunk q*8 within ks*32
  bf16x8 af[4][4];
  auto loadA = [&](int rb) {
    const int arow = rb * 128 + wr * 64 + l15;
#pragma unroll
    for (int mi = 0; mi < 4; ++mi)
#pragma unroll
      for (int ks = 0; ks < 4; ++ks) {
        const ushort* ap = zn + (size_t)(arow + mi * 16) * DIM + ks * 32 + q * 8;
        af[mi][ks] = *reinterpret_cast<const bf16x8*>(ap);
      }
  };

  int rb0, cb0;
  tile_rc(o0, rb0, cb0);
  stage(cb0, 0);       // prologue prefetch
  loadA(rb0);

  float Srow[4][4];
#pragma unroll
  for (int mi = 0; mi < 4; ++mi)
#pragma unroll
    for (int r = 0; r < 4; ++r) Srow[mi][r] = 0.f;

  const float K1 = 2.8853900817779268f;  // (1/TEMP) * log2(e)

  __syncthreads();     // tile 0 staged (vmcnt(0) drained before s_barrier)

  for (int t = 0; t < T; ++t) {
    const int o = o0 + t;
    int trb, tcb;
    tile_rc(o, trb, tcb);
    int nrb = -1, ncb = -1;
    if (t + 1 < T) {
      tile_rc(o + 1, nrb, ncb);
      stage(ncb, (t & 1) ^ 1);   // prefetch next B into idle buffer
    }

    const ushort* bsc = &Bs[t & 1][0];

    f32x4 acc[4][4];
#pragma unroll
    for (int mi = 0; mi < 4; ++mi)
#pragma unroll
      for (int ni = 0; ni < 4; ++ni)
        acc[mi][ni] = (f32x4){0.f, 0.f, 0.f, 0.f};

#pragma unroll
    for (int ks = 0; ks < 4; ++ks) {
      bf16x8 bf[4];
#pragma unroll
      for (int ni = 0; ni < 4; ++ni) {
        const int nl  = wc * 64 + ni * 16 + l15;   // B row in tile (sim col)
        const int ck  = ks * 4 + q;                // k-chunk 0..15
        const int L   = nl * 16 + (ck ^ (nl & 15));
        bf[ni] = *reinterpret_cast<const bf16x8*>(bsc + L * 8);
      }
#pragma unroll
      for (int mi = 0; mi < 4; ++mi)
#pragma unroll
        for (int ni = 0; ni < 4; ++ni)
          acc[mi][ni] = __builtin_amdgcn_mfma_f32_16x16x32_bf16(
              af[mi][ks], bf[ni], acc[mi][ni], 0, 0, 0);
    }

    // Epilogue: v = exp(sim-2) = exp2(K1*dot - K1). Row sums accumulate
    // across the row run; col sums flushed per tile.
    const bool diag = (trb == tcb);
    float Scol[4];
#pragma unroll
    for (int ni = 0; ni < 4; ++ni) Scol[ni] = 0.f;

#pragma unroll
    for (int mi = 0; mi < 4; ++mi)
#pragma unroll
      for (int ni = 0; ni < 4; ++ni)
#pragma unroll
        for (int r = 0; r < 4; ++r) {
          float d = acc[mi][ni][r];
          float v = __builtin_amdgcn_exp2f(fmaf(d, K1, -K1));
          if (diag) {
            const int rl = wr * 64 + mi * 16 + q * 4 + r;
            const int cl = wc * 64 + ni * 16 + l15;
            if (rl == cl) v = 0.f;
          }
          Srow[mi][r] += v;
          Scol[ni]    += v;
        }

    // Positive pairs: tile (rb, rb-32) has sim[i, i-4096] at local rl==cl.
    if (trb - tcb == 32) {
#pragma unroll
      for (int mi = 0; mi < 4; ++mi) {
        const int rl0 = wr * 64 + mi * 16 + q * 4;
#pragma unroll
        for (int ni = 0; ni < 4; ++ni) {
          const int cl = wc * 64 + ni * 16 + l15;
#pragma unroll
          for (int r = 0; r < 4; ++r) {
            if (cl == rl0 + r) {
              const int gr = trb * 128 + rl0 + r;
              const float pv = 2.0f * acc[mi][ni][r];
              P[gr] = pv;
              P[gr - 4096] = pv;   // symmetric partner
            }
          }
        }
      }
    }

    // Col-side flush (skip on diagonal tiles: row-side already covers the
    // full sub-block). Reduce over quads; 16 lanes atomicAdd per ni.
    if (!diag) {
#pragma unroll
      for (int ni = 0; ni < 4; ++ni) {
        float v = Scol[ni];
        v += __shfl_xor(v, 16, 64);
        v += __shfl_xor(v, 32, 64);
        if (lane < 16)
          atomicAdd(&S[tcb * 128 + wc * 64 + ni * 16 + l15], v);
      }
    }

    // Row-side flush at row switch or block end.
    const bool flushR = (t == T - 1) || (nrb != trb);
    if (flushR) {
#pragma unroll
      for (int mi = 0; mi < 4; ++mi)
#pragma unroll
        for (int r = 0; r < 4; ++r) {
          float v = Srow[mi][r];
          v += __shfl_xor(v, 1, 64);
          v += __shfl_xor(v, 2, 64);
          v += __shfl_xor(v, 4, 64);
          v += __shfl_xor(v, 8, 64);
          if (l15 == 0)
            atomicAdd(&S[trb * 128 + wr * 64 + mi * 16 + q * 4 + r], v);
          Srow[mi][r] = 0.f;
        }
    }

    if (t + 1 < T) {
      if (nrb != trb) loadA(nrb);  // one-time A reload at the row switch
      __syncthreads();             // stage(t+1) drained + WAR on Bs[t&1]
    }
  }
}

// ---------------------------------------------------------------------------
// Kernel 3: loss = mean_i( 2 + log(S_i) - P_i )
// ---------------------------------------------------------------------------
__global__ __launch_bounds__(256) void finalize_kernel(
    const float* __restrict__ S, const float* __restrict__ P,
    float* __restrict__ out)
{
  const int i = blockIdx.x * 256 + threadIdx.x;
  float c = 2.0f + logf(S[i]) - P[i];
#pragma unroll
  for (int off = 1; off < 64; off <<= 1)
    c += __shfl_xor(c, off, 64);
  __shared__ float wsum[4];
  const int lane = threadIdx.x & 63, w = threadIdx.x >> 6;
  if (lane == 0) wsum[w] = c;
  __syncthreads();
  if (threadIdx.x == 0)
    atomicAdd(out, (wsum[0] + wsum[1] + wsum[2] + wsum[3]) * (1.0f / NROWS));
}

// ---------------------------------------------------------------------------
extern "C" void kernel_launch(void* const* d_in, const int* in_sizes, int n_in,
                              void* d_out, int out_size, void* d_ws, size_t ws_size,
                              hipStream_t stream)
{
  const float* zx = (const float*)d_in[0];
  const float* zy = (const float*)d_in[1];
  ushort* zn = (ushort*)d_ws;                                      // 2 MiB bf16
  float*  P  = (float*)((char*)d_ws + (size_t)NROWS * DIM * 2);    // 32 KiB
  float*  S  = P + NROWS;                                          // 32 KiB
  float*  out = (float*)d_out;

  hipMemsetAsync(out, 0, sizeof(float), stream);
  normalize_kernel<<<NROWS / 4, 256, 0, stream>>>(zx, zy, zn, S);
  simloss_kernel<<<512, 256, 0, stream>>>(zn, S, P);
  finalize_kernel<<<NROWS / 256, 256, 0, stream>>>(S, P, out);
}

// Round 5
// 83.765 us; speedup vs baseline: 1.0695x; 1.0314x over previous
//
#include <hip/hip_runtime.h>
#include <hip/hip_bf16.h>

#define BATCH 4096
#define NROWS 8192
#define DIM   128
#define NTILE 64

typedef __bf16 bf16x8 __attribute__((ext_vector_type(8)));
typedef __bf16 bf16x2 __attribute__((ext_vector_type(2)));
typedef float  f32x4  __attribute__((ext_vector_type(4)));

typedef const __attribute__((address_space(1))) unsigned int* gptr_t;
typedef __attribute__((address_space(3))) unsigned int* lptr_t;

// ---------------------------------------------------------------------------
// Kernel 1: row-normalize z = concat(zx, zy) -> bf16 zn [8192 x 128].
// One wave per row. Also zero-initializes S (blocks 0..31) and out (block 0)
// so later dispatches can accumulate into poisoned workspace with no memset.
// ---------------------------------------------------------------------------
__global__ __launch_bounds__(256) void normalize_kernel(
    const float* __restrict__ zx, const float* __restrict__ zy,
    ushort* __restrict__ zn, float* __restrict__ S, float* __restrict__ out)
{
  const int tid  = threadIdx.x;
  const int lane = tid & 63;
  const int w    = tid >> 6;
  const int row  = blockIdx.x * 4 + w;
  if (blockIdx.x < 32) S[blockIdx.x * 256 + tid] = 0.f;
  if (blockIdx.x == 0 && tid == 0) out[0] = 0.f;
  const float* src = (row < BATCH) ? (zx + (size_t)row * DIM)
                                   : (zy + (size_t)(row - BATCH) * DIM);
  float2 v = ((const float2*)src)[lane];
  float ss = v.x * v.x + v.y * v.y;
#pragma unroll
  for (int off = 1; off < 64; off <<= 1)
    ss += __shfl_xor(ss, off, 64);
  float inv = 1.0f / fmaxf(sqrtf(ss), 1e-8f);
  bf16x2 st;
  st.x = (__bf16)(v.x * inv);
  st.y = (__bf16)(v.y * inv);
  reinterpret_cast<bf16x2*>(zn + (size_t)row * DIM)[lane] = st;
}

// ---------------------------------------------------------------------------
// Kernel 2 (v5): symmetry-halved + pipelined strips (r4 structure, epilogue
// accumulation vectorized to f32x4 to invite v_pk_add_f32).
// Lower triangle (2080 tiles of 128x128) decomposed into 32 row-PAIRS
// {p, 63-p} of 65 tiles each. Grid = 32 pairs x 16 chunks = 512 blocks
// (exactly 2/CU); chunk 0 takes 5 tiles, chunks 1..15 take 4 (contiguous,
// so each block sees at most ONE row switch -> at most one A-frag reload).
//
// Per tile, exp values feed BOTH row-block and col-block sums (col-side
// skipped on diagonal tiles). Sums -> S[8192] via shfl-reduce + atomicAdd
// (S zeroed by normalize_kernel). Positive-pair tiles (rb-cb==32) write P[i]
// and mirror P[i-4096].
//
// B tiles double-buffered in LDS (2x32 KiB): stage(t+1) -> compute(t) ->
// barrier; stage latency hides under MFMA. A-frags register-resident.
// ---------------------------------------------------------------------------
__global__ __launch_bounds__(256, 2) void simloss_kernel(
    const ushort* __restrict__ zn, float* __restrict__ S,
    float* __restrict__ P)
{
  __shared__ ushort Bs[2][128 * 128];   // 2 x 32 KiB swizzled B tiles
  const int tid  = threadIdx.x;
  const int lane = tid & 63;
  const int w    = tid >> 6;
  const int wr   = w >> 1, wc = w & 1;
  const int q    = lane >> 4;     // quad 0..3
  const int l15  = lane & 15;

  const int p  = blockIdx.x >> 4;            // pair 0..31: rows {p, 63-p}
  const int ch = blockIdx.x & 15;            // chunk 0..15
  const int o0 = (ch == 0) ? 0 : 1 + ch * 4; // seq start: 0,5,9,...,61
  const int T  = (ch == 0) ? 5 : 4;          // tiles in this chunk
  const int L0 = p + 1;                      // tiles in short row (rb = p)

  // seq position o -> tile (rb, cb)
  auto tile_rc = [&](int o, int& rb, int& cb) {
    if (o < L0) { rb = p;      cb = o; }
    else        { rb = 63 - p; cb = o - L0; }
  };

  // Stage B tile for col-block cb into Bs[buf]. Chunk (row, c) -> LDS chunk
  // row*16 + (c ^ (row&15)); global_load_lds dest is uniform base + lane*16,
  // so the swizzle is applied on the per-lane GLOBAL source address.
  auto stage = [&](int cb, int buf) {
    const int C0 = cb * 128;
#pragma unroll
    for (int j = 0; j < 8; ++j) {
      const int Lbase = w * 512 + j * 64;          // uniform per wave
      const int row   = w * 32 + j * 4 + q;        // (Lbase+lane)>>4
      const int c     = l15 ^ (row & 15);
      const ushort* g = zn + (size_t)(C0 + row) * DIM + c * 8;
      __builtin_amdgcn_global_load_lds((gptr_t)g, (lptr_t)(&Bs[buf][Lbase * 8]),
                                       16, 0, 0);
    }
  };

  // A fragments: rows rb*128 + wr*64 + mi*16 + l15, k chunk q*8 within ks*32
  bf16x8 af[4][4];
  auto loadA = [&](int rb) {
    const int arow = rb * 128 + wr * 64 + l15;
#pragma unroll
    for (int mi = 0; mi < 4; ++mi)
#pragma unroll
      for (int ks = 0; ks < 4; ++ks) {
        const ushort* ap = zn + (size_t)(arow + mi * 16) * DIM + ks * 32 + q * 8;
        af[mi][ks] = *reinterpret_cast<const bf16x8*>(ap);
      }
  };

  int rb0, cb0;
  tile_rc(o0, rb0, cb0);
  stage(cb0, 0);       // prologue prefetch
  loadA(rb0);

  f32x4 Srow[4];       // per mi, lanes r=0..3
#pragma unroll
  for (int mi = 0; mi < 4; ++mi) Srow[mi] = (f32x4){0.f, 0.f, 0.f, 0.f};

  const float K1 = 2.8853900817779268f;  // (1/TEMP) * log2(e)

  __syncthreads();     // tile 0 staged (vmcnt(0) drained before s_barrier)

  for (int t = 0; t < T; ++t) {
    const int o = o0 + t;
    int trb, tcb;
    tile_rc(o, trb, tcb);
    int nrb = -1, ncb = -1;
    if (t + 1 < T) {
      tile_rc(o + 1, nrb, ncb);
      stage(ncb, (t & 1) ^ 1);   // prefetch next B into idle buffer
    }

    const ushort* bsc = &Bs[t & 1][0];

    f32x4 acc[4][4];
#pragma unroll
    for (int mi = 0; mi < 4; ++mi)
#pragma unroll
      for (int ni = 0; ni < 4; ++ni)
        acc[mi][ni] = (f32x4){0.f, 0.f, 0.f, 0.f};

#pragma unroll
    for (int ks = 0; ks < 4; ++ks) {
      bf16x8 bf[4];
#pragma unroll
      for (int ni = 0; ni < 4; ++ni) {
        const int nl  = wc * 64 + ni * 16 + l15;   // B row in tile (sim col)
        const int ck  = ks * 4 + q;                // k-chunk 0..15
        const int L   = nl * 16 + (ck ^ (nl & 15));
        bf[ni] = *reinterpret_cast<const bf16x8*>(bsc + L * 8);
      }
#pragma unroll
      for (int mi = 0; mi < 4; ++mi)
#pragma unroll
        for (int ni = 0; ni < 4; ++ni)
          acc[mi][ni] = __builtin_amdgcn_mfma_f32_16x16x32_bf16(
              af[mi][ks], bf[ni], acc[mi][ni], 0, 0, 0);
    }

    // Epilogue: v = exp(sim-2) = exp2(K1*dot - K1). Row sums accumulate
    // across the row run (f32x4 += -> pk_add); col sums flushed per tile.
    const bool diag = (trb == tcb);
    float Scol[4];
#pragma unroll
    for (int ni = 0; ni < 4; ++ni) Scol[ni] = 0.f;

#pragma unroll
    for (int mi = 0; mi < 4; ++mi)
#pragma unroll
      for (int ni = 0; ni < 4; ++ni) {
        f32x4 vv;
#pragma unroll
        for (int r = 0; r < 4; ++r) {
          float d = acc[mi][ni][r];
          float v = __builtin_amdgcn_exp2f(fmaf(d, K1, -K1));
          if (diag) {
            const int rl = wr * 64 + mi * 16 + q * 4 + r;
            const int cl = wc * 64 + ni * 16 + l15;
            if (rl == cl) v = 0.f;
          }
          vv[r] = v;
        }
        Srow[mi] += vv;
        Scol[ni] += (vv[0] + vv[1]) + (vv[2] + vv[3]);
      }

    // Positive pairs: tile (rb, rb-32) has sim[i, i-4096] at local rl==cl.
    if (trb - tcb == 32) {
#pragma unroll
      for (int mi = 0; mi < 4; ++mi) {
        const int rl0 = wr * 64 + mi * 16 + q * 4;
#pragma unroll
        for (int ni = 0; ni < 4; ++ni) {
          const int cl = wc * 64 + ni * 16 + l15;
#pragma unroll
          for (int r = 0; r < 4; ++r) {
            if (cl == rl0 + r) {
              const int gr = trb * 128 + rl0 + r;
              const float pv = 2.0f * acc[mi][ni][r];
              P[gr] = pv;
              P[gr - 4096] = pv;   // symmetric partner
            }
          }
        }
      }
    }

    // Col-side flush (skip on diagonal tiles). Reduce over quads; 16 lanes
    // atomicAdd per ni.
    if (!diag) {
#pragma unroll
      for (int ni = 0; ni < 4; ++ni) {
        float v = Scol[ni];
        v += __shfl_xor(v, 16, 64);
        v += __shfl_xor(v, 32, 64);
        if (lane < 16)
          atomicAdd(&S[tcb * 128 + wc * 64 + ni * 16 + l15], v);
      }
    }

    // Row-side flush at row switch or block end.
    const bool flushR = (t == T - 1) || (nrb != trb);
    if (flushR) {
#pragma unroll
      for (int mi = 0; mi < 4; ++mi)
#pragma unroll
        for (int r = 0; r < 4; ++r) {
          float v = Srow[mi][r];
          v += __shfl_xor(v, 1, 64);
          v += __shfl_xor(v, 2, 64);
          v += __shfl_xor(v, 4, 64);
          v += __shfl_xor(v, 8, 64);
          if (l15 == 0)
            atomicAdd(&S[trb * 128 + wr * 64 + mi * 16 + q * 4 + r], v);
        }
#pragma unroll
      for (int mi = 0; mi < 4; ++mi) Srow[mi] = (f32x4){0.f, 0.f, 0.f, 0.f};
    }

    if (t + 1 < T) {
      if (nrb != trb) loadA(nrb);  // one-time A reload at the row switch
      __syncthreads();             // stage(t+1) drained + WAR on Bs[t&1]
    }
  }
}

// ---------------------------------------------------------------------------
// Kernel 3: loss = mean_i( 2 + log(S_i) - P_i ); out zeroed by normalize.
// ---------------------------------------------------------------------------
__global__ __launch_bounds__(256) void finalize_kernel(
    const float* __restrict__ S, const float* __restrict__ P,
    float* __restrict__ out)
{
  const int i = blockIdx.x * 256 + threadIdx.x;
  float c = 2.0f + logf(S[i]) - P[i];
#pragma unroll
  for (int off = 1; off < 64; off <<= 1)
    c += __shfl_xor(c, off, 64);
  __shared__ float wsum[4];
  const int lane = threadIdx.x & 63, w = threadIdx.x >> 6;
  if (lane == 0) wsum[w] = c;
  __syncthreads();
  if (threadIdx.x == 0)
    atomicAdd(out, (wsum[0] + wsum[1] + wsum[2] + wsum[3]) * (1.0f / NROWS));
}

// ---------------------------------------------------------------------------
extern "C" void kernel_launch(void* const* d_in, const int* in_sizes, int n_in,
                              void* d_out, int out_size, void* d_ws, size_t ws_size,
                              hipStream_t stream)
{
  const float* zx = (const float*)d_in[0];
  const float* zy = (const float*)d_in[1];
  ushort* zn = (ushort*)d_ws;                                      // 2 MiB bf16
  float*  P  = (float*)((char*)d_ws + (size_t)NROWS * DIM * 2);    // 32 KiB
  float*  S  = P + NROWS;                                          // 32 KiB
  float*  out = (float*)d_out;

  normalize_kernel<<<NROWS / 4, 256, 0, stream>>>(zx, zy, zn, S, out);
  simloss_kernel<<<512, 256, 0, stream>>>(zn, S, P);
  finalize_kernel<<<NROWS / 256, 256, 0, stream>>>(S, P, out);
}